// Round 7
// baseline (428.822 us; speedup 1.0000x reference)
//
#include <hip/hip_runtime.h>
#include <cmath>

#define BATCH 8
#define SEQ 1024
#define DMODEL 1024
#define NHEAD 16
#define HDIM 64

typedef _Float16 f16x8 __attribute__((ext_vector_type(8)));
typedef _Float16 f16x4 __attribute__((ext_vector_type(4)));
typedef _Float16 f16x2 __attribute__((ext_vector_type(2)));
typedef float    f32x4 __attribute__((ext_vector_type(4)));

// ================= f16 MFMA GEMM body (audited rounds 3-6) =================
// ALAYOUT 0: A row-major [M,K]        ALAYOUT 1: A is [B,H,S,D] as [M,K=H*D]
// BLAYOUT 0: B is [NHEAD,K,HDIM]      BLAYOUT 1: B row-major [K,N]
// OLAYOUT 0: C stored [B,H,S,D]       OLAYOUT 1: C row-major [M,N]
// k-order self-consistency: A and B frags use the same assumed k-map
// (k=(lane>>4)*8+i), so any shared hardware k-permutation cancels in the
// contraction. C/D map is the verified col=lane&15, row=(lane>>4)*4+reg.
// LDS: As[128][72] row-major (144B rows -> b128 accesses spread all banks);
//      Bs transposed [n][k] with 16B-slot XOR swizzle slot^((n>>1)&7):
//      frag reads 2-way (free), staging writes ~4-way instead of 16-way.
template<int ALAYOUT, int BLAYOUT, int OLAYOUT>
__device__ __forceinline__
void gemm_body(const float* __restrict__ A, const float* __restrict__ Bm,
               const float* __restrict__ bias, float* __restrict__ C,
               int M, int N, int K)
{
    constexpr int BM = 128, BN = 128, BK = 64;
    alignas(16) __shared__ _Float16 As[128][72];
    alignas(16) __shared__ _Float16 Bs[128 * 72];

    const int t    = threadIdx.x;
    const int lane = t & 63;
    const int w    = t >> 6;
    const int wr   = w >> 1, wc = w & 1;   // wave -> 64x64 quadrant
    const int q    = lane >> 4, r = lane & 15;
    const int m0   = blockIdx.y * BM;
    const int n0   = blockIdx.x * BN;

    f32x4 acc[4][4];
    #pragma unroll
    for (int i = 0; i < 4; ++i)
        #pragma unroll
        for (int j = 0; j < 4; ++j)
            acc[i][j] = (f32x4){0.f, 0.f, 0.f, 0.f};

    for (int kt = 0; kt < K / BK; ++kt) {
        const int k0 = kt * BK;
        __syncthreads();
        // ---- stage A ----
        {
            const int kq = (t & 15) << 2;
            #pragma unroll
            for (int j = 0; j < 8; ++j) {
                const int row = (t >> 4) + j * 16;
                const float* src;
                if (ALAYOUT == 0) {
                    src = &A[(size_t)(m0 + row) * K + k0 + kq];
                } else {
                    const int gm = m0 + row;
                    const int bb = gm >> 10, s = gm & 1023;
                    const int h = (k0 + kq) >> 6, d = (k0 + kq) & 63;
                    src = &A[((((size_t)bb * NHEAD + h) << 10) + s) * HDIM + d];
                }
                const float4 v = *(const float4*)src;
                f16x4 hv = { (_Float16)v.x, (_Float16)v.y,
                             (_Float16)v.z, (_Float16)v.w };
                *(f16x4*)&As[row][kq] = hv;
            }
        }
        // ---- stage B transposed + 16B-slot XOR swizzle ----
        {
            const int n4 = (t & 31) << 2;
            const int kb = (t >> 5) << 3;
            #pragma unroll
            for (int j = 0; j < 2; ++j) {
                const int k4 = kb + j * 4;
                float4 v[4];
                #pragma unroll
                for (int rr = 0; rr < 4; ++rr) {
                    const float* src;
                    if (BLAYOUT == 0) {
                        const int n = n0 + n4;
                        const int h = n >> 6, d = n & 63;
                        src = &Bm[((size_t)h * K + (k0 + k4 + rr)) * HDIM + d];
                    } else {
                        src = &Bm[(size_t)(k0 + k4 + rr) * N + n0 + n4];
                    }
                    v[rr] = *(const float4*)src;
                }
                const int slot = k4 >> 3;              // == t>>5 for both j
                #pragma unroll
                for (int c = 0; c < 4; ++c) {
                    const int n  = n4 + c;
                    const int sw = (n >> 1) & 7;
                    _Float16* dst = &Bs[0] + n * 72 + ((slot ^ sw) << 3) + (k4 & 7);
                    f16x4 hv = { (_Float16)(((const float*)&v[0])[c]),
                                 (_Float16)(((const float*)&v[1])[c]),
                                 (_Float16)(((const float*)&v[2])[c]),
                                 (_Float16)(((const float*)&v[3])[c]) };
                    *(f16x4*)dst = hv;
                }
            }
        }
        __syncthreads();
        // ---- compute: 2 k-halves x 16 fragment MFMAs ----
        #pragma unroll
        for (int h = 0; h < 2; ++h) {
            f16x8 a[4], b[4];
            #pragma unroll
            for (int mf = 0; mf < 4; ++mf) {
                const int mrow = wr * 64 + mf * 16 + r;
                a[mf] = *(const f16x8*)&As[mrow][h * 32 + q * 8];
            }
            #pragma unroll
            for (int nf = 0; nf < 4; ++nf) {
                const int n  = wc * 64 + nf * 16 + r;
                const int p  = (h * 4 + q) ^ ((n >> 1) & 7);
                b[nf] = *(const f16x8*)(&Bs[0] + n * 72 + (p << 3));
            }
            #pragma unroll
            for (int mf = 0; mf < 4; ++mf)
                #pragma unroll
                for (int nf = 0; nf < 4; ++nf)
                    acc[mf][nf] = __builtin_amdgcn_mfma_f32_16x16x32_f16(
                        a[mf], b[nf], acc[mf][nf], 0, 0, 0);
        }
    }

    // ---- epilogue: C/D map col=lane&15, row=(lane>>4)*4+reg (verified) ----
    #pragma unroll
    for (int mf = 0; mf < 4; ++mf) {
        #pragma unroll
        for (int nf = 0; nf < 4; ++nf) {
            const int col = n0 + wc * 64 + nf * 16 + r;
            const float bv = bias[col];
            #pragma unroll
            for (int i = 0; i < 4; ++i) {
                const int row = m0 + wr * 64 + mf * 16 + q * 4 + i;
                const float val = acc[mf][nf][i] + bv;
                if (OLAYOUT == 0) {
                    const int bb = row >> 10, s = row & 1023;
                    const int h = col >> 6, d = col & 63;
                    C[((((size_t)bb * NHEAD + h) << 10) + s) * HDIM + d] = val;
                } else {
                    C[(size_t)row * N + col] = val;
                }
            }
        }
    }
}

// ---- fused QKV projections: one launch, blockIdx.z selects the GEMM ----
__global__ __launch_bounds__(256)
void gemm_qkv(const float* __restrict__ Q, const float* __restrict__ K,
              const float* __restrict__ V,
              const float* __restrict__ Wq, const float* __restrict__ Wk,
              const float* __restrict__ Wv,
              const float* __restrict__ bq, const float* __restrict__ bk,
              const float* __restrict__ bv,
              float* __restrict__ Qh, float* __restrict__ Kh,
              float* __restrict__ Vh, int M, int N, int Kd)
{
    const int z = blockIdx.z;                       // uniform per block
    const float* A    = (z == 0) ? Q  : (z == 1) ? K  : V;
    const float* B    = (z == 0) ? Wq : (z == 1) ? Wk : Wv;
    const float* bias = (z == 0) ? bq : (z == 1) ? bk : bv;
    float*       C    = (z == 0) ? Qh : (z == 1) ? Kh : Vh;
    gemm_body<0, 0, 0>(A, B, bias, C, M, N, Kd);
}

// ---- output projection ----
__global__ __launch_bounds__(256)
void gemm_out(const float* __restrict__ A, const float* __restrict__ Bm,
              const float* __restrict__ bias, float* __restrict__ C,
              int M, int N, int K)
{
    gemm_body<1, 1, 1>(A, Bm, bias, C, M, N, K);
}

// ================= MFMA flash attention (audited rounds 4-6) ===============
// 8 waves/block, 16 query rows/wave (128 rows/block), 64-key tiles.
// QK^T and PV via mfma_f32_16x16x32_f16; both accumulators share the verified
// C/D map so per-row online-softmax state lines up by construction.
// Masking: x*0.03125 - 1e9 per element, identical fp ops to reference;
// pad==0 -> every score exactly -1e9 -> uniform softmax over ALL keys (quirk);
// fully-masked processed tiles contribute exactly 0 (exp underflow is exact).
// In-place output over QX: each wave reads only its own 16 rows (before any
// write) and writes them at the end -> race-free.
__global__ __launch_bounds__(512, 4)
void attn_mfma(float* __restrict__ QX, const float* __restrict__ Kh,
               const float* __restrict__ Vh, const int* __restrict__ pad)
{
    alignas(16) __shared__ _Float16 Klds[64][72];
    alignas(16) __shared__ _Float16 VT[64][72];
    alignas(16) __shared__ _Float16 Plds[8][16][72];

    const int tid  = threadIdx.x;
    const int w    = tid >> 6;
    const int lane = tid & 63;
    const int qq   = lane >> 4;      // 0..3
    const int r    = lane & 15;      // 0..15
    const int bh   = blockIdx.y;
    const int b    = bh >> 4;
    const int s0   = blockIdx.x << 7;            // 128 rows per block
    const int padb = pad[b];
    const size_t base = (size_t)bh * SEQ * HDIM;
    const int mrow = s0 + w * 16;                // wave's first query row

    // Q fragments (A-operand): row m = mrow + r, k(d) = kh*32 + qq*8 + j
    f16x8 qf[2];
    #pragma unroll
    for (int kh = 0; kh < 2; ++kh) {
        const float* src = &QX[base + (size_t)(mrow + r) * HDIM + kh * 32 + qq * 8];
        const float4 v0 = *(const float4*)src;
        const float4 v1 = *(const float4*)(src + 4);
        qf[kh] = (f16x8){ (_Float16)v0.x, (_Float16)v0.y, (_Float16)v0.z, (_Float16)v0.w,
                          (_Float16)v1.x, (_Float16)v1.y, (_Float16)v1.z, (_Float16)v1.w };
    }

    const int kvlim = (padb == 0) ? SEQ : (SEQ - padb);
    const int Lblk  = (padb == 0) ? SEQ : min(s0 + 128, SEQ - padb);
    const int nt    = (Lblk + 63) >> 6;

    float mrun[4], lrun[4];
    f32x4 accO[4];
    #pragma unroll
    for (int i = 0; i < 4; ++i) {
        mrun[i] = -3.0e38f; lrun[i] = 0.f;
        accO[i] = (f32x4){0.f, 0.f, 0.f, 0.f};
    }

    for (int kt = 0; kt < nt; ++kt) {
        const int t0 = kt << 6;
        __syncthreads();                          // prev-tile readers done
        // ---- stage K: Klds[t][d] (f16), 2x float4 per thread ----
        {
            const int tk = tid >> 3, d8 = (tid & 7) << 3;
            const float* src = &Kh[base + (size_t)(t0 + tk) * HDIM + d8];
            const float4 v0 = *(const float4*)src;
            const float4 v1 = *(const float4*)(src + 4);
            *(f16x8*)&Klds[tk][d8] =
                (f16x8){ (_Float16)v0.x, (_Float16)v0.y, (_Float16)v0.z, (_Float16)v0.w,
                         (_Float16)v1.x, (_Float16)v1.y, (_Float16)v1.z, (_Float16)v1.w };
        }
        // ---- stage V transposed: VT[d][t], f16x2-packed pair writes ----
        {
            const int tp = tid >> 4, dq = tid & 15;   // rows 2tp,2tp+1; cols 4dq..
            const float* src = &Vh[base + (size_t)(t0 + 2 * tp) * HDIM + 4 * dq];
            const float4 a0 = *(const float4*)src;
            const float4 a1 = *(const float4*)(src + HDIM);
            const float* f0 = (const float*)&a0;
            const float* f1 = (const float*)&a1;
            #pragma unroll
            for (int c = 0; c < 4; ++c)
                *(f16x2*)&VT[4 * dq + c][2 * tp] =
                    (f16x2){ (_Float16)f0[c], (_Float16)f1[c] };
        }
        __syncthreads();

        // ---- QK^T: sacc[tg] -> score(m = mrow+qq*4+i, t = t0+tg*16+r) ----
        f32x4 sacc[4];
        #pragma unroll
        for (int tg = 0; tg < 4; ++tg) sacc[tg] = (f32x4){0.f, 0.f, 0.f, 0.f};
        #pragma unroll
        for (int tg = 0; tg < 4; ++tg)
            #pragma unroll
            for (int kh = 0; kh < 2; ++kh) {
                const f16x8 kf = *(const f16x8*)&Klds[tg * 16 + r][kh * 32 + qq * 8];
                sacc[tg] = __builtin_amdgcn_mfma_f32_16x16x32_f16(qf[kh], kf, sacc[tg], 0, 0, 0);
            }

        // ---- mask + online softmax (per row i, 16-lane-group reduces) ----
        float sc[4][4];
        #pragma unroll
        for (int tg = 0; tg < 4; ++tg) {
            const int tt = t0 + tg * 16 + r;
            #pragma unroll
            for (int i = 0; i < 4; ++i) {
                const int mm = mrow + qq * 4 + i;
                float x = sacc[tg][i] * 0.03125f;          // 1/sqrt(1024)
                if (tt > mm || tt >= kvlim || padb == 0)
                    x -= 1.0e9f;                           // same fp op as ref
                sc[tg][i] = x;
            }
        }
        float p[4][4], scale[4];
        #pragma unroll
        for (int i = 0; i < 4; ++i) {
            float mx = fmaxf(fmaxf(sc[0][i], sc[1][i]), fmaxf(sc[2][i], sc[3][i]));
            #pragma unroll
            for (int off = 1; off < 16; off <<= 1)
                mx = fmaxf(mx, __shfl_xor(mx, off));
            const float mn = fmaxf(mrun[i], mx);
            scale[i] = __expf(mrun[i] - mn);
            mrun[i] = mn;
            float ls = 0.f;
            #pragma unroll
            for (int tg = 0; tg < 4; ++tg) {
                const float pv = __expf(sc[tg][i] - mn);   // ==0 exact if masked
                p[tg][i] = pv;
                ls += pv;
            }
            #pragma unroll
            for (int off = 1; off < 16; off <<= 1)
                ls += __shfl_xor(ls, off);
            lrun[i] = lrun[i] * scale[i] + ls;
        }

        // ---- P relayout via wave-private LDS: [m_loc][t_loc] f16 ----
        #pragma unroll
        for (int tg = 0; tg < 4; ++tg)
            #pragma unroll
            for (int i = 0; i < 4; ++i)
                Plds[w][qq * 4 + i][tg * 16 + r] = (_Float16)p[tg][i];
        asm volatile("s_waitcnt lgkmcnt(0)" ::: "memory");
        __builtin_amdgcn_wave_barrier();

        const f16x8 pa0 = *(const f16x8*)&Plds[w][r][qq * 8];        // k=t 0..31
        const f16x8 pa1 = *(const f16x8*)&Plds[w][r][32 + qq * 8];   // k=t 32..63

        // ---- PV: accO[dg] over d = dg*16+r, rows shared with sacc map ----
        #pragma unroll
        for (int dg = 0; dg < 4; ++dg) {
            #pragma unroll
            for (int i = 0; i < 4; ++i) accO[dg][i] *= scale[i];
            const f16x8 v0f = *(const f16x8*)&VT[dg * 16 + r][qq * 8];
            const f16x8 v1f = *(const f16x8*)&VT[dg * 16 + r][32 + qq * 8];
            accO[dg] = __builtin_amdgcn_mfma_f32_16x16x32_f16(pa0, v0f, accO[dg], 0, 0, 0);
            accO[dg] = __builtin_amdgcn_mfma_f32_16x16x32_f16(pa1, v1f, accO[dg], 0, 0, 0);
        }
    }

    // ---- epilogue: in-place over QX (wave-private rows) ----
    #pragma unroll
    for (int dg = 0; dg < 4; ++dg)
        #pragma unroll
        for (int i = 0; i < 4; ++i)
            QX[base + (size_t)(mrow + qq * 4 + i) * HDIM + dg * 16 + r] =
                accO[dg][i] / lrun[i];
}

// ================= launcher ================================================
extern "C" void kernel_launch(void* const* d_in, const int* in_sizes, int n_in,
                              void* d_out, int out_size, void* d_ws, size_t ws_size,
                              hipStream_t stream)
{
    const float* Q  = (const float*)d_in[0];
    const float* K  = (const float*)d_in[1];
    const float* V  = (const float*)d_in[2];
    const int*  pad = (const int*)d_in[3];
    const float* Wq = (const float*)d_in[4];
    const float* bq = (const float*)d_in[5];
    const float* Wk = (const float*)d_in[6];
    const float* bk = (const float*)d_in[7];
    const float* Wv = (const float*)d_in[8];
    const float* bv = (const float*)d_in[9];
    const float* Wo = (const float*)d_in[10];
    const float* bo = (const float*)d_in[11];
    float* out = (float*)d_out;

    float* ws = (float*)d_ws;
    const size_t per = (size_t)BATCH * NHEAD * SEQ * HDIM;   // 8M floats
    float* Qh = ws;                 // also attention output (in-place)
    float* Kh = ws + per;
    float* Vh = ws + 2 * per;       // total ws use: 96 MB

    const int M = BATCH * SEQ;      // 8192
    dim3 gq(DMODEL / 128, M / 128, 3);   // fused Q/K/V projections
    gemm_qkv<<<gq, 256, 0, stream>>>(Q, K, V, Wq, Wk, Wv, bq, bk, bv,
                                     Qh, Kh, Vh, M, DMODEL, DMODEL);

    attn_mfma<<<dim3(SEQ / 128, BATCH * NHEAD), 512, 0, stream>>>(Qh, Kh, Vh, pad);

    gemm_out<<<dim3(DMODEL / 128, M / 128), 256, 0, stream>>>(Qh, Wo, bo, out, M, DMODEL, DMODEL);
}

// Round 8
// 371.472 us; speedup vs baseline: 1.1544x; 1.1544x over previous
//
#include <hip/hip_runtime.h>
#include <cmath>

#define BATCH 8
#define SEQ 1024
#define DMODEL 1024
#define NHEAD 16
#define HDIM 64
#define USE_GLOAD 1

typedef _Float16 f16x8 __attribute__((ext_vector_type(8)));
typedef _Float16 f16x4 __attribute__((ext_vector_type(4)));
typedef _Float16 f16x2 __attribute__((ext_vector_type(2)));
typedef float    f32x4 __attribute__((ext_vector_type(4)));

// ---------------- ws layout (bytes), peak 88MB (96MB proven OK round 7) ----
// [ 0,16M)  Qf16 [8192][1024]      -> after gemm_q: Vh f16 [B,H,S,D] (gemm_v)
// [16,32M)  Kf16                   -> after gemm_k: X f16 [8192][1024] (attn)
// [32,48M)  Vf16
// [48,50M) WqT  [50,52M) WkT  [52,54M) WvT  [54,56M) WoT   (f16 [n][k])
// [56,72M)  Qh f16 [B,H,S,D]
// [72,88M)  Kh f16 [B,H,S,D]

// ================= prologue: fp32 -> f16 convert ===========================
__global__ __launch_bounds__(256)
void prep_cvt(const float* __restrict__ Q, const float* __restrict__ K,
              const float* __restrict__ V, _Float16* __restrict__ Qf,
              _Float16* __restrict__ Kf, _Float16* __restrict__ Vf)
{
    const int n = (8192 * 1024) / 4;                 // float4 count
    const float*   src = (blockIdx.y == 0) ? Q : (blockIdx.y == 1) ? K : V;
    _Float16*      dst = (blockIdx.y == 0) ? Qf : (blockIdx.y == 1) ? Kf : Vf;
    for (int i = blockIdx.x * 256 + threadIdx.x; i < n; i += gridDim.x * 256) {
        const float4 v = ((const float4*)src)[i];
        ((f16x4*)dst)[i] = (f16x4){ (_Float16)v.x, (_Float16)v.y,
                                    (_Float16)v.z, (_Float16)v.w };
    }
}

// ================= prologue: W transpose -> f16 [n][k] =====================
// z<3: W[h][k][d] -> WT[h*64+d][k].  z=3: Wo[k][n] -> WoT[n][k].
__global__ __launch_bounds__(256)
void prep_tr(const float* __restrict__ Wq, const float* __restrict__ Wk,
             const float* __restrict__ Wv, const float* __restrict__ Wo,
             _Float16* __restrict__ WqT, _Float16* __restrict__ WkT,
             _Float16* __restrict__ WvT, _Float16* __restrict__ WoT)
{
    __shared__ float L[64][65];
    const int z  = blockIdx.z;
    const int t  = threadIdx.x;
    const float*    W  = (z == 0) ? Wq : (z == 1) ? Wk : (z == 2) ? Wv : Wo;
    _Float16*       WT = (z == 0) ? WqT : (z == 1) ? WkT : (z == 2) ? WvT : WoT;
    const int k0 = blockIdx.y * 64;
    const int n0 = blockIdx.x * 64;     // z<3: == h*64
    const int kr = t >> 2, c4 = (t & 3) * 16;
    const float* src = (z < 3)
        ? &W[((size_t)blockIdx.x * DMODEL + (k0 + kr)) * HDIM + c4]
        : &W[(size_t)(k0 + kr) * DMODEL + n0 + c4];
    #pragma unroll
    for (int j = 0; j < 4; ++j) {
        const float4 v = *(const float4*)(src + j * 4);
        L[kr][c4 + j * 4 + 0] = v.x; L[kr][c4 + j * 4 + 1] = v.y;
        L[kr][c4 + j * 4 + 2] = v.z; L[kr][c4 + j * 4 + 3] = v.w;
    }
    __syncthreads();
    const int d = t >> 2, kk = (t & 3) * 16;
    f16x8 o0, o1;
    #pragma unroll
    for (int j = 0; j < 8; ++j) {
        o0[j] = (_Float16)L[kk + j][d];
        o1[j] = (_Float16)L[kk + 8 + j][d];
    }
    *(f16x8*)&WT[(size_t)(n0 + d) * DMODEL + k0 + kk]     = o0;
    *(f16x8*)&WT[(size_t)(n0 + d) * DMODEL + k0 + kk + 8] = o1;
}

// ================= f16 GEMM, global_load_lds staging =======================
// A [M][K] f16 row-major; BT [N][K] f16 row-major. 128x128 tile, BK=64,
// 4 waves (64x64 quadrant each). LDS linear [row][64] granule-swizzled:
// granule slot s of row holds col-octet o = s ^ (row&7)  (involution), so
// gload_lds (linear dest, per-lane swizzled SOURCE gather) + swizzled
// ds_read_b128 are conflict-free (quarter-wave: 8 slots x 2 rows).
// k-map self-consistency: A and B frags both use k=(h*4+lane>>4)*8+i.
// C/D map: col=lane&15, row=(lane>>4)*4+reg (verified).
// OLAYOUT 0: f16 out in [B,H,S,D]; OLAYOUT 1: fp32 out [M][N].
template<int OLAYOUT>
__global__ __launch_bounds__(256)
void gemm_f16(const _Float16* __restrict__ A, const _Float16* __restrict__ BT,
              const float* __restrict__ bias, float* __restrict__ Cf,
              _Float16* __restrict__ Ch)
{
    constexpr int Kd = DMODEL;
    alignas(16) __shared__ _Float16 Al[128 * 64];
    alignas(16) __shared__ _Float16 Bl[128 * 64];

    const int t    = threadIdx.x;
    const int lane = t & 63;
    const int w    = t >> 6;
    const int wr   = w >> 1, wc = w & 1;
    const int q    = lane >> 4, r = lane & 15;
    const int m0   = blockIdx.y * 128;
    const int n0   = blockIdx.x * 128;
    const int srow = lane >> 3;      // 0..7
    const int sslot = lane & 7;

    f32x4 acc[4][4];
    #pragma unroll
    for (int i = 0; i < 4; ++i)
        #pragma unroll
        for (int j = 0; j < 4; ++j)
            acc[i][j] = (f32x4){0.f, 0.f, 0.f, 0.f};

    for (int kt = 0; kt < Kd / 64; ++kt) {
        const int k0 = kt * 64;
        #pragma unroll
        for (int j = 0; j < 4; ++j) {
            const int rowA = w * 32 + j * 8 + srow;
            const int colA = ((sslot ^ (rowA & 7)) << 3);
#if USE_GLOAD
            __builtin_amdgcn_global_load_lds(
                (const __attribute__((address_space(1))) void*)
                    &A[(size_t)(m0 + rowA) * Kd + k0 + colA],
                (__attribute__((address_space(3))) void*)&Al[(w * 32 + j * 8) * 64],
                16, 0, 0);
#else
            *(f16x8*)&Al[(size_t)rowA * 64 + (sslot << 3)] =
                *(const f16x8*)&A[(size_t)(m0 + rowA) * Kd + k0 + colA];
#endif
        }
        #pragma unroll
        for (int j = 0; j < 4; ++j) {
            const int rowB = w * 32 + j * 8 + srow;
            const int colB = ((sslot ^ (rowB & 7)) << 3);
#if USE_GLOAD
            __builtin_amdgcn_global_load_lds(
                (const __attribute__((address_space(1))) void*)
                    &BT[(size_t)(n0 + rowB) * Kd + k0 + colB],
                (__attribute__((address_space(3))) void*)&Bl[(w * 32 + j * 8) * 64],
                16, 0, 0);
#else
            *(f16x8*)&Bl[(size_t)rowB * 64 + (sslot << 3)] =
                *(const f16x8*)&BT[(size_t)(n0 + rowB) * Kd + k0 + colB];
#endif
        }
        __syncthreads();             // drains vmcnt -> staged data visible
        #pragma unroll
        for (int h = 0; h < 2; ++h) {
            f16x8 a[4], b[4];
            #pragma unroll
            for (int mf = 0; mf < 4; ++mf) {
                const int row = wr * 64 + mf * 16 + r;
                a[mf] = *(const f16x8*)&Al[row * 64 + (((h * 4 + q) ^ (row & 7)) << 3)];
            }
            #pragma unroll
            for (int nf = 0; nf < 4; ++nf) {
                const int row = wc * 64 + nf * 16 + r;
                b[nf] = *(const f16x8*)&Bl[row * 64 + (((h * 4 + q) ^ (row & 7)) << 3)];
            }
            #pragma unroll
            for (int mf = 0; mf < 4; ++mf)
                #pragma unroll
                for (int nf = 0; nf < 4; ++nf)
                    acc[mf][nf] = __builtin_amdgcn_mfma_f32_16x16x32_f16(
                        a[mf], b[nf], acc[mf][nf], 0, 0, 0);
        }
        __syncthreads();             // protect LDS before next-tile staging
    }

    #pragma unroll
    for (int mf = 0; mf < 4; ++mf) {
        #pragma unroll
        for (int nf = 0; nf < 4; ++nf) {
            const int col = n0 + wc * 64 + nf * 16 + r;
            const float bv = bias[col];
            #pragma unroll
            for (int i = 0; i < 4; ++i) {
                const int row = m0 + wr * 64 + mf * 16 + q * 4 + i;
                const float val = acc[mf][nf][i] + bv;
                if (OLAYOUT == 0) {
                    const int bb = row >> 10, s = row & 1023;
                    const int h = col >> 6, d = col & 63;
                    Ch[((((size_t)bb * NHEAD + h) << 10) + s) * HDIM + d] = (_Float16)val;
                } else {
                    Cf[(size_t)row * DMODEL + col] = val;
                }
            }
        }
    }
}

// ================= MFMA flash attention (f16 in, f16 out) ==================
// Structure/masking/softmax identical to round 7 (PASSED, absmax 0.0078125);
// only the I/O dtype and K-staging (now gload_lds + swizzle) changed. All
// fp32->f16 roundings occur at the same values -> numerics byte-identical.
__global__ __launch_bounds__(512, 4)
void attn_mfma(const _Float16* __restrict__ Qh, const _Float16* __restrict__ Kh,
               const _Float16* __restrict__ Vh, const int* __restrict__ pad,
               _Float16* __restrict__ X)
{
    alignas(16) __shared__ _Float16 Klds[64 * 64];   // granule-swizzled
    alignas(16) __shared__ _Float16 VT[64][72];      // [d][t], reg-transposed
    alignas(16) __shared__ _Float16 Plds[8][16][72];

    const int tid  = threadIdx.x;
    const int w    = tid >> 6;
    const int lane = tid & 63;
    const int qq   = lane >> 4;
    const int r    = lane & 15;
    const int bh   = blockIdx.y;
    const int b    = bh >> 4;
    const int hh   = bh & 15;
    const int s0   = blockIdx.x << 7;
    const int padb = pad[b];
    const size_t base = (size_t)bh * SEQ * HDIM;
    const int mrow = s0 + w * 16;

    f16x8 qf[2];
    #pragma unroll
    for (int kh = 0; kh < 2; ++kh)
        qf[kh] = *(const f16x8*)&Qh[base + (size_t)(mrow + r) * HDIM + kh * 32 + qq * 8];

    const int kvlim = (padb == 0) ? SEQ : (SEQ - padb);
    const int Lblk  = (padb == 0) ? SEQ : min(s0 + 128, SEQ - padb);
    const int nt    = (Lblk + 63) >> 6;

    float mrun[4], lrun[4];
    f32x4 accO[4];
    #pragma unroll
    for (int i = 0; i < 4; ++i) {
        mrun[i] = -3.0e38f; lrun[i] = 0.f;
        accO[i] = (f32x4){0.f, 0.f, 0.f, 0.f};
    }

    const int krow  = w * 8 + (lane >> 3);   // K-staging coords
    const int kslot = lane & 7;
    const int tp = tid >> 4, dq = tid & 15;  // V-staging coords

    for (int kt = 0; kt < nt; ++kt) {
        const int t0 = kt << 6;
        __syncthreads();                      // prev-tile readers done
        // ---- stage K: gload_lds, swizzled source, linear dest ----
#if USE_GLOAD
        __builtin_amdgcn_global_load_lds(
            (const __attribute__((address_space(1))) void*)
                &Kh[base + (size_t)(t0 + krow) * HDIM + ((kslot ^ (krow & 7)) << 3)],
            (__attribute__((address_space(3))) void*)&Klds[w * 8 * 64],
            16, 0, 0);
#else
        *(f16x8*)&Klds[krow * 64 + (kslot << 3)] =
            *(const f16x8*)&Kh[base + (size_t)(t0 + krow) * HDIM + ((kslot ^ (krow & 7)) << 3)];
#endif
        // ---- stage V transposed: VT[d][t], f16x2-packed pair writes ----
        {
            const f16x4 a0 = *(const f16x4*)&Vh[base + (size_t)(t0 + 2 * tp) * HDIM + 4 * dq];
            const f16x4 a1 = *(const f16x4*)&Vh[base + (size_t)(t0 + 2 * tp + 1) * HDIM + 4 * dq];
            #pragma unroll
            for (int c = 0; c < 4; ++c)
                *(f16x2*)&VT[4 * dq + c][2 * tp] = (f16x2){ a0[c], a1[c] };
        }
        __syncthreads();

        // ---- QK^T ----
        f32x4 sacc[4];
        #pragma unroll
        for (int tg = 0; tg < 4; ++tg) sacc[tg] = (f32x4){0.f, 0.f, 0.f, 0.f};
        #pragma unroll
        for (int tg = 0; tg < 4; ++tg)
            #pragma unroll
            for (int kh = 0; kh < 2; ++kh) {
                const int kr = tg * 16 + r;
                const f16x8 kf = *(const f16x8*)
                    &Klds[kr * 64 + (((kh * 4 + qq) ^ (kr & 7)) << 3)];
                sacc[tg] = __builtin_amdgcn_mfma_f32_16x16x32_f16(qf[kh], kf, sacc[tg], 0, 0, 0);
            }

        // ---- mask + online softmax ----
        float sc[4][4];
        #pragma unroll
        for (int tg = 0; tg < 4; ++tg) {
            const int tt = t0 + tg * 16 + r;
            #pragma unroll
            for (int i = 0; i < 4; ++i) {
                const int mm = mrow + qq * 4 + i;
                float x = sacc[tg][i] * 0.03125f;        // 1/sqrt(1024)
                if (tt > mm || tt >= kvlim || padb == 0)
                    x -= 1.0e9f;                         // same fp op as ref
                sc[tg][i] = x;
            }
        }
        float p[4][4], scale[4];
        #pragma unroll
        for (int i = 0; i < 4; ++i) {
            float mx = fmaxf(fmaxf(sc[0][i], sc[1][i]), fmaxf(sc[2][i], sc[3][i]));
            #pragma unroll
            for (int off = 1; off < 16; off <<= 1)
                mx = fmaxf(mx, __shfl_xor(mx, off));
            const float mn = fmaxf(mrun[i], mx);
            scale[i] = __expf(mrun[i] - mn);
            mrun[i] = mn;
            float ls = 0.f;
            #pragma unroll
            for (int tg = 0; tg < 4; ++tg) {
                const float pv = __expf(sc[tg][i] - mn);
                p[tg][i] = pv;
                ls += pv;
            }
            #pragma unroll
            for (int off = 1; off < 16; off <<= 1)
                ls += __shfl_xor(ls, off);
            lrun[i] = lrun[i] * scale[i] + ls;
        }

        // ---- P relayout (wave-private) ----
        #pragma unroll
        for (int tg = 0; tg < 4; ++tg)
            #pragma unroll
            for (int i = 0; i < 4; ++i)
                Plds[w][qq * 4 + i][tg * 16 + r] = (_Float16)p[tg][i];
        asm volatile("s_waitcnt lgkmcnt(0)" ::: "memory");
        __builtin_amdgcn_wave_barrier();

        const f16x8 pa0 = *(const f16x8*)&Plds[w][r][qq * 8];
        const f16x8 pa1 = *(const f16x8*)&Plds[w][r][32 + qq * 8];

        // ---- PV ----
        #pragma unroll
        for (int dg = 0; dg < 4; ++dg) {
            #pragma unroll
            for (int i = 0; i < 4; ++i) accO[dg][i] *= scale[i];
            const f16x8 v0f = *(const f16x8*)&VT[dg * 16 + r][qq * 8];
            const f16x8 v1f = *(const f16x8*)&VT[dg * 16 + r][32 + qq * 8];
            accO[dg] = __builtin_amdgcn_mfma_f32_16x16x32_f16(pa0, v0f, accO[dg], 0, 0, 0);
            accO[dg] = __builtin_amdgcn_mfma_f32_16x16x32_f16(pa1, v1f, accO[dg], 0, 0, 0);
        }
    }

    // ---- epilogue: X f16 [B,S,H*D] row-major (feeds out-proj A) ----
    #pragma unroll
    for (int dg = 0; dg < 4; ++dg)
        #pragma unroll
        for (int i = 0; i < 4; ++i)
            X[((size_t)b * SEQ + (mrow + qq * 4 + i)) * DMODEL + hh * HDIM + dg * 16 + r] =
                (_Float16)(accO[dg][i] / lrun[i]);
}

// ================= launcher ================================================
extern "C" void kernel_launch(void* const* d_in, const int* in_sizes, int n_in,
                              void* d_out, int out_size, void* d_ws, size_t ws_size,
                              hipStream_t stream)
{
    const float* Q  = (const float*)d_in[0];
    const float* K  = (const float*)d_in[1];
    const float* V  = (const float*)d_in[2];
    const int*  pad = (const int*)d_in[3];
    const float* Wq = (const float*)d_in[4];
    const float* bq = (const float*)d_in[5];
    const float* Wk = (const float*)d_in[6];
    const float* bk = (const float*)d_in[7];
    const float* Wv = (const float*)d_in[8];
    const float* bv = (const float*)d_in[9];
    const float* Wo = (const float*)d_in[10];
    const float* bo = (const float*)d_in[11];
    float* out = (float*)d_out;

    char* ws = (char*)d_ws;
    const size_t MB = 1024 * 1024;
    _Float16* Qf16 = (_Float16*)(ws + 0 * MB);
    _Float16* Kf16 = (_Float16*)(ws + 16 * MB);
    _Float16* Vf16 = (_Float16*)(ws + 32 * MB);
    _Float16* WqT  = (_Float16*)(ws + 48 * MB);
    _Float16* WkT  = (_Float16*)(ws + 50 * MB);
    _Float16* WvT  = (_Float16*)(ws + 52 * MB);
    _Float16* WoT  = (_Float16*)(ws + 54 * MB);
    _Float16* Qh   = (_Float16*)(ws + 56 * MB);
    _Float16* Kh   = (_Float16*)(ws + 72 * MB);
    _Float16* Vh   = (_Float16*)(ws + 0 * MB);    // aliases dead Qf16
    _Float16* X    = (_Float16*)(ws + 16 * MB);   // aliases dead Kf16

    prep_cvt<<<dim3(1024, 3), 256, 0, stream>>>(Q, K, V, Qf16, Kf16, Vf16);
    prep_tr <<<dim3(16, 16, 4), 256, 0, stream>>>(Wq, Wk, Wv, Wo, WqT, WkT, WvT, WoT);

    dim3 gg(DMODEL / 128, (BATCH * SEQ) / 128);   // (8, 64)
    gemm_f16<0><<<gg, 256, 0, stream>>>(Qf16, WqT, bq, nullptr, Qh);
    gemm_f16<0><<<gg, 256, 0, stream>>>(Kf16, WkT, bk, nullptr, Kh);
    gemm_f16<0><<<gg, 256, 0, stream>>>(Vf16, WvT, bv, nullptr, Vh);  // Vh over Qf16 (dead)

    attn_mfma<<<dim3(SEQ / 128, BATCH * NHEAD), 512, 0, stream>>>(Qh, Kh, Vh, pad, X);

    gemm_f16<1><<<gg, 256, 0, stream>>>(X, WoT, bo, out, nullptr);
}

// Round 11
// 371.398 us; speedup vs baseline: 1.1546x; 1.0002x over previous
//
#include <hip/hip_runtime.h>
#include <cmath>

#define BATCH 8
#define SEQ 1024
#define DMODEL 1024
#define NHEAD 16
#define HDIM 64
#define USE_GLOAD 1

typedef _Float16 f16x8 __attribute__((ext_vector_type(8)));
typedef _Float16 f16x4 __attribute__((ext_vector_type(4)));
typedef _Float16 f16x2 __attribute__((ext_vector_type(2)));
typedef float    f32x4 __attribute__((ext_vector_type(4)));

// ---------------- ws layout (bytes) ----------------------------------------
// [ 0,16M) Qf16            -> after gemm_q: Vh f16 [B,H,S,D]
// [16,32M) Kf16            -> after gemm_k: VT f16 [B,H,D,S]
// [32,48M) Vf16            -> after gemm_v: X  f16 [B,S,H*D]
// [48,50M) WqT [50,52M) WkT [52,54M) WvT [54,56M) WoT   (f16 [n][k])
// [56,72M) Qh f16 [B,H,S,D]
// [72,88M) Kh f16 [B,H,S,D]

// ================= prologue: fp32 -> f16 convert ===========================
__global__ __launch_bounds__(256)
void prep_cvt(const float* __restrict__ Q, const float* __restrict__ K,
              const float* __restrict__ V, _Float16* __restrict__ Qf,
              _Float16* __restrict__ Kf, _Float16* __restrict__ Vf)
{
    const int n = (8192 * 1024) / 4;
    const float*   src = (blockIdx.y == 0) ? Q : (blockIdx.y == 1) ? K : V;
    _Float16*      dst = (blockIdx.y == 0) ? Qf : (blockIdx.y == 1) ? Kf : Vf;
    for (int i = blockIdx.x * 256 + threadIdx.x; i < n; i += gridDim.x * 256) {
        const float4 v = ((const float4*)src)[i];
        ((f16x4*)dst)[i] = (f16x4){ (_Float16)v.x, (_Float16)v.y,
                                    (_Float16)v.z, (_Float16)v.w };
    }
}

// ================= prologue: W transpose -> f16 [n][k] =====================
__global__ __launch_bounds__(256)
void prep_tr(const float* __restrict__ Wq, const float* __restrict__ Wk,
             const float* __restrict__ Wv, const float* __restrict__ Wo,
             _Float16* __restrict__ WqT, _Float16* __restrict__ WkT,
             _Float16* __restrict__ WvT, _Float16* __restrict__ WoT)
{
    __shared__ float L[64][65];
    const int z  = blockIdx.z;
    const int t  = threadIdx.x;
    const float*    W  = (z == 0) ? Wq : (z == 1) ? Wk : (z == 2) ? Wv : Wo;
    _Float16*       WT = (z == 0) ? WqT : (z == 1) ? WkT : (z == 2) ? WvT : WoT;
    const int k0 = blockIdx.y * 64;
    const int n0 = blockIdx.x * 64;
    const int kr = t >> 2, c4 = (t & 3) * 16;
    const float* src = (z < 3)
        ? &W[((size_t)blockIdx.x * DMODEL + (k0 + kr)) * HDIM + c4]
        : &W[(size_t)(k0 + kr) * DMODEL + n0 + c4];
    #pragma unroll
    for (int j = 0; j < 4; ++j) {
        const float4 v = *(const float4*)(src + j * 4);
        L[kr][c4 + j * 4 + 0] = v.x; L[kr][c4 + j * 4 + 1] = v.y;
        L[kr][c4 + j * 4 + 2] = v.z; L[kr][c4 + j * 4 + 3] = v.w;
    }
    __syncthreads();
    const int d = t >> 2, kk = (t & 3) * 16;
    f16x8 o0, o1;
    #pragma unroll
    for (int j = 0; j < 8; ++j) {
        o0[j] = (_Float16)L[kk + j][d];
        o1[j] = (_Float16)L[kk + 8 + j][d];
    }
    *(f16x8*)&WT[(size_t)(n0 + d) * DMODEL + k0 + kk]     = o0;
    *(f16x8*)&WT[(size_t)(n0 + d) * DMODEL + k0 + kk + 8] = o1;
}

// ================= Vh [B,H,S,D] -> VT [B,H,D,S] ============================
__global__ __launch_bounds__(256)
void transpose_v(const _Float16* __restrict__ Vh, _Float16* __restrict__ VT)
{
    __shared__ _Float16 L[64][72];
    const int bh = blockIdx.y;
    const int s0 = blockIdx.x * 64;
    const int t  = threadIdx.x;
    const size_t base = (size_t)bh * SEQ * HDIM;   // == bh*65536 both views
    {
        const _Float16* src = &Vh[base + (size_t)(s0 + (t >> 2)) * HDIM + (t & 3) * 16];
        *(f16x8*)&L[t >> 2][(t & 3) * 16]     = *(const f16x8*)src;
        *(f16x8*)&L[t >> 2][(t & 3) * 16 + 8] = *(const f16x8*)(src + 8);
    }
    __syncthreads();
    const int d = t >> 2, sq = (t & 3) * 16;
    f16x8 o0, o1;
    #pragma unroll
    for (int j = 0; j < 8; ++j) {
        o0[j] = L[sq + j][d];
        o1[j] = L[sq + 8 + j][d];
    }
    _Float16* dst = &VT[base + (size_t)d * SEQ + s0 + sq];
    *(f16x8*)dst       = o0;
    *(f16x8*)(dst + 8) = o1;
}

// ================= f16 GEMM, global_load_lds staging (round-8, PASSED) =====
template<int OLAYOUT>
__global__ __launch_bounds__(256)
void gemm_f16(const _Float16* __restrict__ A, const _Float16* __restrict__ BT,
              const float* __restrict__ bias, float* __restrict__ Cf,
              _Float16* __restrict__ Ch)
{
    constexpr int Kd = DMODEL;
    alignas(16) __shared__ _Float16 Al[128 * 64];
    alignas(16) __shared__ _Float16 Bl[128 * 64];

    const int t    = threadIdx.x;
    const int lane = t & 63;
    const int w    = t >> 6;
    const int wr   = w >> 1, wc = w & 1;
    const int q    = lane >> 4, r = lane & 15;
    const int m0   = blockIdx.y * 128;
    const int n0   = blockIdx.x * 128;
    const int srow = lane >> 3;
    const int sslot = lane & 7;

    f32x4 acc[4][4];
    #pragma unroll
    for (int i = 0; i < 4; ++i)
        #pragma unroll
        for (int j = 0; j < 4; ++j)
            acc[i][j] = (f32x4){0.f, 0.f, 0.f, 0.f};

    for (int kt = 0; kt < Kd / 64; ++kt) {
        const int k0 = kt * 64;
        #pragma unroll
        for (int j = 0; j < 4; ++j) {
            const int rowA = w * 32 + j * 8 + srow;
            const int colA = ((sslot ^ (rowA & 7)) << 3);
            __builtin_amdgcn_global_load_lds(
                (const __attribute__((address_space(1))) void*)
                    &A[(size_t)(m0 + rowA) * Kd + k0 + colA],
                (__attribute__((address_space(3))) void*)&Al[(w * 32 + j * 8) * 64],
                16, 0, 0);
        }
        #pragma unroll
        for (int j = 0; j < 4; ++j) {
            const int rowB = w * 32 + j * 8 + srow;
            const int colB = ((sslot ^ (rowB & 7)) << 3);
            __builtin_amdgcn_global_load_lds(
                (const __attribute__((address_space(1))) void*)
                    &BT[(size_t)(n0 + rowB) * Kd + k0 + colB],
                (__attribute__((address_space(3))) void*)&Bl[(w * 32 + j * 8) * 64],
                16, 0, 0);
        }
        __syncthreads();
        #pragma unroll
        for (int h = 0; h < 2; ++h) {
            f16x8 a[4], b[4];
            #pragma unroll
            for (int mf = 0; mf < 4; ++mf) {
                const int row = wr * 64 + mf * 16 + r;
                a[mf] = *(const f16x8*)&Al[row * 64 + (((h * 4 + q) ^ (row & 7)) << 3)];
            }
            #pragma unroll
            for (int nf = 0; nf < 4; ++nf) {
                const int row = wc * 64 + nf * 16 + r;
                b[nf] = *(const f16x8*)&Bl[row * 64 + (((h * 4 + q) ^ (row & 7)) << 3)];
            }
            #pragma unroll
            for (int mf = 0; mf < 4; ++mf)
                #pragma unroll
                for (int nf = 0; nf < 4; ++nf)
                    acc[mf][nf] = __builtin_amdgcn_mfma_f32_16x16x32_f16(
                        a[mf], b[nf], acc[mf][nf], 0, 0, 0);
        }
        __syncthreads();
    }

    #pragma unroll
    for (int mf = 0; mf < 4; ++mf) {
        #pragma unroll
        for (int nf = 0; nf < 4; ++nf) {
            const int col = n0 + wc * 64 + nf * 16 + r;
            const float bv = bias[col];
            #pragma unroll
            for (int i = 0; i < 4; ++i) {
                const int row = m0 + wr * 64 + mf * 16 + q * 4 + i;
                const float val = acc[mf][nf][i] + bv;
                if (OLAYOUT == 0) {
                    const int bb = row >> 10, s = row & 1023;
                    const int h = col >> 6, d = col & 63;
                    Ch[((((size_t)bb * NHEAD + h) << 10) + s) * HDIM + d] = (_Float16)val;
                } else {
                    Cf[(size_t)row * DMODEL + col] = val;
                }
            }
        }
    }
}

// ================= MFMA flash attention (all-LDS at conflict floor) ========
// 4 waves/block, 64 query rows/block (16/wave), 64-key tiles, grid (16,128).
// K and V^T both staged via global_load_lds with granule-XOR source swizzle
// (linear [row][64] LDS, slot = octet ^ (row&7)) -> reads AND stages at the
// full-bank floor. P relayout in swizzled [16][64] per-wave LDS. Numerics
// identical to rounds 7/8 (same values, same op order): absmax tripwire
// 0.0078125. Masking: x*0.03125 - 1e9, exact -1e9 collapse; pad==0 ->
// uniform softmax over all keys (reference quirk); skipped tiles exact-0.
__global__ __launch_bounds__(256)
void attn_mfma(const _Float16* __restrict__ Qh, const _Float16* __restrict__ Kh,
               const _Float16* __restrict__ VT, const int* __restrict__ pad,
               _Float16* __restrict__ X)
{
    alignas(16) __shared__ _Float16 Klds[64 * 64];
    alignas(16) __shared__ _Float16 Vlds[64 * 64];   // [d][t-local], swizzled
    alignas(16) __shared__ _Float16 Plds[4][16 * 64];

    const int tid  = threadIdx.x;
    const int w    = tid >> 6;
    const int lane = tid & 63;
    const int qq   = lane >> 4;
    const int r    = lane & 15;
    const int bh   = blockIdx.y;
    const int b    = bh >> 4;
    const int hh   = bh & 15;
    const int s0   = blockIdx.x << 6;            // 64 rows per block
    const int padb = pad[b];
    const size_t base = (size_t)bh * SEQ * HDIM; // Qh/Kh [B,H,S,D]; VT same size
    const int mrow = s0 + w * 16;

    f16x8 qf[2];
    #pragma unroll
    for (int kh = 0; kh < 2; ++kh)
        qf[kh] = *(const f16x8*)&Qh[base + (size_t)(mrow + r) * HDIM + kh * 32 + qq * 8];

    const int kvlim = (padb == 0) ? SEQ : (SEQ - padb);
    const int Lblk  = (padb == 0) ? SEQ : min(s0 + 64, SEQ - padb);
    const int nt    = (Lblk + 63) >> 6;

    float mrun[4], lrun[4];
    f32x4 accO[4];
    #pragma unroll
    for (int i = 0; i < 4; ++i) {
        mrun[i] = -3.0e38f; lrun[i] = 0.f;
        accO[i] = (f32x4){0.f, 0.f, 0.f, 0.f};
    }

    const int srow  = lane >> 3;   // 0..7
    const int sslot = lane & 7;

    for (int kt = 0; kt < nt; ++kt) {
        const int t0 = kt << 6;
        __syncthreads();                      // prev-tile readers done
        // ---- stage K tile rows (t-local) via gload_lds, swizzled source ----
        #pragma unroll
        for (int j = 0; j < 2; ++j) {
            const int row = j * 32 + w * 8 + srow;
            const int col = ((sslot ^ (row & 7)) << 3);
            __builtin_amdgcn_global_load_lds(
                (const __attribute__((address_space(1))) void*)
                    &Kh[base + (size_t)(t0 + row) * HDIM + col],
                (__attribute__((address_space(3))) void*)&Klds[(j * 32 + w * 8) * 64],
                16, 0, 0);
        }
        // ---- stage V^T tile rows (d) via gload_lds, swizzled source ----
        #pragma unroll
        for (int j = 0; j < 2; ++j) {
            const int row = j * 32 + w * 8 + srow;       // d-row
            const int col = ((sslot ^ (row & 7)) << 3);  // t-offset in tile
            __builtin_amdgcn_global_load_lds(
                (const __attribute__((address_space(1))) void*)
                    &VT[base + (size_t)row * SEQ + t0 + col],
                (__attribute__((address_space(3))) void*)&Vlds[(j * 32 + w * 8) * 64],
                16, 0, 0);
        }
        __syncthreads();

        // ---- QK^T: sacc[tg] -> score(m = mrow+qq*4+i, t = t0+tg*16+r) ----
        f32x4 sacc[4];
        #pragma unroll
        for (int tg = 0; tg < 4; ++tg) sacc[tg] = (f32x4){0.f, 0.f, 0.f, 0.f};
        #pragma unroll
        for (int tg = 0; tg < 4; ++tg)
            #pragma unroll
            for (int kh = 0; kh < 2; ++kh) {
                const int kr = tg * 16 + r;
                const f16x8 kf = *(const f16x8*)
                    &Klds[kr * 64 + (((kh * 4 + qq) ^ (kr & 7)) << 3)];
                sacc[tg] = __builtin_amdgcn_mfma_f32_16x16x32_f16(qf[kh], kf, sacc[tg], 0, 0, 0);
            }

        // ---- mask + online softmax (identical ops to rounds 7/8) ----
        float sc[4][4];
        #pragma unroll
        for (int tg = 0; tg < 4; ++tg) {
            const int tt = t0 + tg * 16 + r;
            #pragma unroll
            for (int i = 0; i < 4; ++i) {
                const int mm = mrow + qq * 4 + i;
                float x = sacc[tg][i] * 0.03125f;        // 1/sqrt(1024)
                if (tt > mm || tt >= kvlim || padb == 0)
                    x -= 1.0e9f;                         // same fp op as ref
                sc[tg][i] = x;
            }
        }
        float p[4][4], scale[4];
        #pragma unroll
        for (int i = 0; i < 4; ++i) {
            float mx = fmaxf(fmaxf(sc[0][i], sc[1][i]), fmaxf(sc[2][i], sc[3][i]));
            #pragma unroll
            for (int off = 1; off < 16; off <<= 1)
                mx = fmaxf(mx, __shfl_xor(mx, off));
            const float mn = fmaxf(mrun[i], mx);
            scale[i] = __expf(mrun[i] - mn);
            mrun[i] = mn;
            float ls = 0.f;
            #pragma unroll
            for (int tg = 0; tg < 4; ++tg) {
                const float pv = __expf(sc[tg][i] - mn);
                p[tg][i] = pv;
                ls += pv;
            }
            #pragma unroll
            for (int off = 1; off < 16; off <<= 1)
                ls += __shfl_xor(ls, off);
            lrun[i] = lrun[i] * scale[i] + ls;
        }

        // ---- P relayout: swizzled [m][t] per-wave LDS ----
        #pragma unroll
        for (int tg = 0; tg < 4; ++tg)
            #pragma unroll
            for (int i = 0; i < 4; ++i) {
                const int m  = qq * 4 + i;
                const int tt = tg * 16 + r;
                Plds[w][m * 64 + (((tt >> 3) ^ (m & 7)) << 3) + (tt & 7)] =
                    (_Float16)p[tg][i];
            }
        asm volatile("s_waitcnt lgkmcnt(0)" ::: "memory");
        __builtin_amdgcn_wave_barrier();

        f16x8 pa[2];
        #pragma unroll
        for (int kh = 0; kh < 2; ++kh)
            pa[kh] = *(const f16x8*)
                &Plds[w][r * 64 + (((kh * 4 + qq) ^ (r & 7)) << 3)];

        // ---- PV: accO[dg], B-operand from swizzled Vlds rows (d) ----
        #pragma unroll
        for (int dg = 0; dg < 4; ++dg) {
            #pragma unroll
            for (int i = 0; i < 4; ++i) accO[dg][i] *= scale[i];
            #pragma unroll
            for (int kh = 0; kh < 2; ++kh) {
                const int vrow = dg * 16 + r;
                const f16x8 vf = *(const f16x8*)
                    &Vlds[vrow * 64 + (((kh * 4 + qq) ^ (vrow & 7)) << 3)];
                accO[dg] = __builtin_amdgcn_mfma_f32_16x16x32_f16(pa[kh], vf, accO[dg], 0, 0, 0);
            }
        }
    }

    // ---- epilogue: X f16 [B,S,H*D] (feeds out-proj A) ----
    #pragma unroll
    for (int dg = 0; dg < 4; ++dg)
        #pragma unroll
        for (int i = 0; i < 4; ++i)
            X[((size_t)b * SEQ + (mrow + qq * 4 + i)) * DMODEL + hh * HDIM + dg * 16 + r] =
                (_Float16)(accO[dg][i] / lrun[i]);
}

// ================= launcher ================================================
extern "C" void kernel_launch(void* const* d_in, const int* in_sizes, int n_in,
                              void* d_out, int out_size, void* d_ws, size_t ws_size,
                              hipStream_t stream)
{
    const float* Q  = (const float*)d_in[0];
    const float* K  = (const float*)d_in[1];
    const float* V  = (const float*)d_in[2];
    const int*  pad = (const int*)d_in[3];
    const float* Wq = (const float*)d_in[4];
    const float* bq = (const float*)d_in[5];
    const float* Wk = (const float*)d_in[6];
    const float* bk = (const float*)d_in[7];
    const float* Wv = (const float*)d_in[8];
    const float* bv = (const float*)d_in[9];
    const float* Wo = (const float*)d_in[10];
    const float* bo = (const float*)d_in[11];
    float* out = (float*)d_out;

    char* ws = (char*)d_ws;
    const size_t MB = 1024 * 1024;
    _Float16* Qf16 = (_Float16*)(ws + 0 * MB);
    _Float16* Kf16 = (_Float16*)(ws + 16 * MB);
    _Float16* Vf16 = (_Float16*)(ws + 32 * MB);
    _Float16* WqT  = (_Float16*)(ws + 48 * MB);
    _Float16* WkT  = (_Float16*)(ws + 50 * MB);
    _Float16* WvT  = (_Float16*)(ws + 52 * MB);
    _Float16* WoT  = (_Float16*)(ws + 54 * MB);
    _Float16* Qh   = (_Float16*)(ws + 56 * MB);
    _Float16* Kh   = (_Float16*)(ws + 72 * MB);
    _Float16* Vh   = (_Float16*)(ws + 0 * MB);    // over dead Qf16
    _Float16* VT   = (_Float16*)(ws + 16 * MB);   // over dead Kf16
    _Float16* X    = (_Float16*)(ws + 32 * MB);   // over dead Vf16

    prep_cvt<<<dim3(1024, 3), 256, 0, stream>>>(Q, K, V, Qf16, Kf16, Vf16);
    prep_tr <<<dim3(16, 16, 4), 256, 0, stream>>>(Wq, Wk, Wv, Wo, WqT, WkT, WvT, WoT);

    dim3 gg(DMODEL / 128, (BATCH * SEQ) / 128);   // (8, 64)
    gemm_f16<0><<<gg, 256, 0, stream>>>(Qf16, WqT, bq, nullptr, Qh);
    gemm_f16<0><<<gg, 256, 0, stream>>>(Kf16, WkT, bk, nullptr, Kh);
    gemm_f16<0><<<gg, 256, 0, stream>>>(Vf16, WvT, bv, nullptr, Vh);

    transpose_v<<<dim3(SEQ / 64, BATCH * NHEAD), 256, 0, stream>>>(Vh, VT);

    attn_mfma<<<dim3(SEQ / 64, BATCH * NHEAD), 256, 0, stream>>>(Qh, Kh, VT, pad, X);

    gemm_f16<1><<<gg, 256, 0, stream>>>(X, WoT, bo, out, nullptr);
}

// Round 13
// 356.177 us; speedup vs baseline: 1.2040x; 1.0427x over previous
//
#include <hip/hip_runtime.h>
#include <cmath>

#define BATCH 8
#define SEQ 1024
#define DMODEL 1024
#define NHEAD 16
#define HDIM 64

typedef _Float16 f16x8 __attribute__((ext_vector_type(8)));
typedef _Float16 f16x4 __attribute__((ext_vector_type(4)));
typedef _Float16 f16x2 __attribute__((ext_vector_type(2)));
typedef float    f32x4 __attribute__((ext_vector_type(4)));

// ---------------- ws layout (bytes) ----------------------------------------
// [ 0,16M) Qf16            -> after gemm_q: Vh f16 [B,H,S,D]
// [16,32M) Kf16            -> after gemm_k: VT f16 [B,H,D,S]
// [32,48M) Vf16            -> after gemm_v: X  f16 [B,S,H*D]
// [48,50M) WqT [50,52M) WkT [52,54M) WvT [54,56M) WoT   (f16 [n][k])
// [56,72M) Qh f16 [B,H,S,D]
// [72,88M) Kh f16 [B,H,S,D]

// ================= prologue: fp32 -> f16 convert ===========================
__global__ __launch_bounds__(256)
void prep_cvt(const float* __restrict__ Q, const float* __restrict__ K,
              const float* __restrict__ V, _Float16* __restrict__ Qf,
              _Float16* __restrict__ Kf, _Float16* __restrict__ Vf)
{
    const int n = (8192 * 1024) / 4;
    const float*   src = (blockIdx.y == 0) ? Q : (blockIdx.y == 1) ? K : V;
    _Float16*      dst = (blockIdx.y == 0) ? Qf : (blockIdx.y == 1) ? Kf : Vf;
    for (int i = blockIdx.x * 256 + threadIdx.x; i < n; i += gridDim.x * 256) {
        const float4 v = ((const float4*)src)[i];
        ((f16x4*)dst)[i] = (f16x4){ (_Float16)v.x, (_Float16)v.y,
                                    (_Float16)v.z, (_Float16)v.w };
    }
}

// ================= prologue: W transpose -> f16 [n][k] =====================
__global__ __launch_bounds__(256)
void prep_tr(const float* __restrict__ Wq, const float* __restrict__ Wk,
             const float* __restrict__ Wv, const float* __restrict__ Wo,
             _Float16* __restrict__ WqT, _Float16* __restrict__ WkT,
             _Float16* __restrict__ WvT, _Float16* __restrict__ WoT)
{
    __shared__ float L[64][65];
    const int z  = blockIdx.z;
    const int t  = threadIdx.x;
    const float*    W  = (z == 0) ? Wq : (z == 1) ? Wk : (z == 2) ? Wv : Wo;
    _Float16*       WT = (z == 0) ? WqT : (z == 1) ? WkT : (z == 2) ? WvT : WoT;
    const int k0 = blockIdx.y * 64;
    const int n0 = blockIdx.x * 64;
    const int kr = t >> 2, c4 = (t & 3) * 16;
    const float* src = (z < 3)
        ? &W[((size_t)blockIdx.x * DMODEL + (k0 + kr)) * HDIM + c4]
        : &W[(size_t)(k0 + kr) * DMODEL + n0 + c4];
    #pragma unroll
    for (int j = 0; j < 4; ++j) {
        const float4 v = *(const float4*)(src + j * 4);
        L[kr][c4 + j * 4 + 0] = v.x; L[kr][c4 + j * 4 + 1] = v.y;
        L[kr][c4 + j * 4 + 2] = v.z; L[kr][c4 + j * 4 + 3] = v.w;
    }
    __syncthreads();
    const int d = t >> 2, kk = (t & 3) * 16;
    f16x8 o0, o1;
    #pragma unroll
    for (int j = 0; j < 8; ++j) {
        o0[j] = (_Float16)L[kk + j][d];
        o1[j] = (_Float16)L[kk + 8 + j][d];
    }
    *(f16x8*)&WT[(size_t)(n0 + d) * DMODEL + k0 + kk]     = o0;
    *(f16x8*)&WT[(size_t)(n0 + d) * DMODEL + k0 + kk + 8] = o1;
}

// ================= Vh [B,H,S,D] -> VT [B,H,D,S] ============================
__global__ __launch_bounds__(256)
void transpose_v(const _Float16* __restrict__ Vh, _Float16* __restrict__ VT)
{
    __shared__ _Float16 L[64][72];
    const int bh = blockIdx.y;
    const int s0 = blockIdx.x * 64;
    const int t  = threadIdx.x;
    const size_t base = (size_t)bh * SEQ * HDIM;
    {
        const _Float16* src = &Vh[base + (size_t)(s0 + (t >> 2)) * HDIM + (t & 3) * 16];
        *(f16x8*)&L[t >> 2][(t & 3) * 16]     = *(const f16x8*)src;
        *(f16x8*)&L[t >> 2][(t & 3) * 16 + 8] = *(const f16x8*)(src + 8);
    }
    __syncthreads();
    const int d = t >> 2, sq = (t & 3) * 16;
    f16x8 o0, o1;
    #pragma unroll
    for (int j = 0; j < 8; ++j) {
        o0[j] = L[sq + j][d];
        o1[j] = L[sq + 8 + j][d];
    }
    _Float16* dst = &VT[base + (size_t)d * SEQ + s0 + sq];
    *(f16x8*)dst       = o0;
    *(f16x8*)(dst + 8) = o1;
}

// ================= f16 GEMM body (round-8/11 structure, PASSED twice) ======
template<int OLAYOUT>
__device__ __forceinline__
void gemm_body(const _Float16* __restrict__ A, const _Float16* __restrict__ BT,
               const float* __restrict__ bias, float* __restrict__ Cf,
               _Float16* __restrict__ Ch)
{
    constexpr int Kd = DMODEL;
    alignas(16) __shared__ _Float16 Al[128 * 64];
    alignas(16) __shared__ _Float16 Bl[128 * 64];

    const int t    = threadIdx.x;
    const int lane = t & 63;
    const int w    = t >> 6;
    const int wr   = w >> 1, wc = w & 1;
    const int q    = lane >> 4, r = lane & 15;
    const int m0   = blockIdx.y * 128;
    const int n0   = blockIdx.x * 128;
    const int srow = lane >> 3;
    const int sslot = lane & 7;

    f32x4 acc[4][4];
    #pragma unroll
    for (int i = 0; i < 4; ++i)
        #pragma unroll
        for (int j = 0; j < 4; ++j)
            acc[i][j] = (f32x4){0.f, 0.f, 0.f, 0.f};

    for (int kt = 0; kt < Kd / 64; ++kt) {
        const int k0 = kt * 64;
        #pragma unroll
        for (int j = 0; j < 4; ++j) {
            const int rowA = w * 32 + j * 8 + srow;
            const int colA = ((sslot ^ (rowA & 7)) << 3);
            __builtin_amdgcn_global_load_lds(
                (const __attribute__((address_space(1))) void*)
                    &A[(size_t)(m0 + rowA) * Kd + k0 + colA],
                (__attribute__((address_space(3))) void*)&Al[(w * 32 + j * 8) * 64],
                16, 0, 0);
        }
        #pragma unroll
        for (int j = 0; j < 4; ++j) {
            const int rowB = w * 32 + j * 8 + srow;
            const int colB = ((sslot ^ (rowB & 7)) << 3);
            __builtin_amdgcn_global_load_lds(
                (const __attribute__((address_space(1))) void*)
                    &BT[(size_t)(n0 + rowB) * Kd + k0 + colB],
                (__attribute__((address_space(3))) void*)&Bl[(w * 32 + j * 8) * 64],
                16, 0, 0);
        }
        __syncthreads();
        #pragma unroll
        for (int h = 0; h < 2; ++h) {
            f16x8 a[4], b[4];
            #pragma unroll
            for (int mf = 0; mf < 4; ++mf) {
                const int row = wr * 64 + mf * 16 + r;
                a[mf] = *(const f16x8*)&Al[row * 64 + (((h * 4 + q) ^ (row & 7)) << 3)];
            }
            #pragma unroll
            for (int nf = 0; nf < 4; ++nf) {
                const int row = wc * 64 + nf * 16 + r;
                b[nf] = *(const f16x8*)&Bl[row * 64 + (((h * 4 + q) ^ (row & 7)) << 3)];
            }
            #pragma unroll
            for (int mf = 0; mf < 4; ++mf)
                #pragma unroll
                for (int nf = 0; nf < 4; ++nf)
                    acc[mf][nf] = __builtin_amdgcn_mfma_f32_16x16x32_f16(
                        a[mf], b[nf], acc[mf][nf], 0, 0, 0);
        }
        __syncthreads();
    }

    #pragma unroll
    for (int mf = 0; mf < 4; ++mf) {
        #pragma unroll
        for (int nf = 0; nf < 4; ++nf) {
            const int col = n0 + wc * 64 + nf * 16 + r;
            const float bv = bias[col];
            #pragma unroll
            for (int i = 0; i < 4; ++i) {
                const int row = m0 + wr * 64 + mf * 16 + q * 4 + i;
                const float val = acc[mf][nf][i] + bv;
                if (OLAYOUT == 0) {
                    const int bb = row >> 10, s = row & 1023;
                    const int h = col >> 6, d = col & 63;
                    Ch[((((size_t)bb * NHEAD + h) << 10) + s) * HDIM + d] = (_Float16)val;
                } else {
                    Cf[(size_t)row * DMODEL + col] = val;
                }
            }
        }
    }
}

// ---- fused QKV projections (one dispatch; also surfaces in rocprof top-5) --
__global__ __launch_bounds__(256)
void gemm_qkv(const _Float16* __restrict__ Qf, const _Float16* __restrict__ Kf,
              const _Float16* __restrict__ Vf,
              const _Float16* __restrict__ WqT, const _Float16* __restrict__ WkT,
              const _Float16* __restrict__ WvT,
              const float* __restrict__ bq, const float* __restrict__ bk,
              const float* __restrict__ bv,
              _Float16* __restrict__ Qh, _Float16* __restrict__ Kh,
              _Float16* __restrict__ Vh)
{
    const int z = blockIdx.z;                       // uniform per block
    const _Float16* A  = (z == 0) ? Qf  : (z == 1) ? Kf  : Vf;
    const _Float16* BT = (z == 0) ? WqT : (z == 1) ? WkT : WvT;
    const float*  bias = (z == 0) ? bq  : (z == 1) ? bk  : bv;
    _Float16*     Ch   = (z == 0) ? Qh  : (z == 1) ? Kh  : Vh;
    gemm_body<0>(A, BT, bias, nullptr, Ch);
}

__global__ __launch_bounds__(256)
void gemm_out(const _Float16* __restrict__ A, const _Float16* __restrict__ BT,
              const float* __restrict__ bias, float* __restrict__ C)
{
    gemm_body<1>(A, BT, bias, C, nullptr);
}

// ================= MFMA flash attention, causal-paired q-tiles =============
// Grid (8,128): block bx handles q-tiles {bx, 15-bx} -> (bx+1)+(16-bx) = 17
// K-tiles/block at small pad (was 1..16, mean 8.5, tail-bound at 23% avg
// occupancy). 1024 blocks x 24KB = exactly 4 blocks/CU, all co-resident,
// uniform completion. Per-phase body identical to round 11 (PASSED, 0 bank
// conflicts): K/V^T staged via global_load_lds granule-XOR (linear dest,
// inverse-swizzled source, swizzled read); P relayout swizzled per-wave.
// Numerics/op order unchanged -> absmax tripwire 0.0078125. Masking:
// x*0.03125 - 1e9 exact collapse; pad==0 -> uniform softmax (ref quirk).
__global__ __launch_bounds__(256)
void attn_mfma(const _Float16* __restrict__ Qh, const _Float16* __restrict__ Kh,
               const _Float16* __restrict__ VT, const int* __restrict__ pad,
               _Float16* __restrict__ X)
{
    alignas(16) __shared__ _Float16 Klds[64 * 64];
    alignas(16) __shared__ _Float16 Vlds[64 * 64];
    alignas(16) __shared__ _Float16 Plds[4][16 * 64];

    const int tid  = threadIdx.x;
    const int w    = tid >> 6;
    const int lane = tid & 63;
    const int qq   = lane >> 4;
    const int r    = lane & 15;
    const int bx   = blockIdx.x;                 // 0..7
    const int bh   = blockIdx.y;
    const int b    = bh >> 4;
    const int hh   = bh & 15;
    const int padb = pad[b];
    const size_t base = (size_t)bh * SEQ * HDIM;
    const int kvlim = (padb == 0) ? SEQ : (SEQ - padb);

    const int srow  = lane >> 3;   // 0..7
    const int sslot = lane & 7;

    #pragma unroll
    for (int ph = 0; ph < 2; ++ph) {
        const int qx   = (ph == 0) ? bx : (15 - bx);
        const int s0   = qx << 6;
        const int mrow = s0 + w * 16;

        f16x8 qf[2];
        #pragma unroll
        for (int kh = 0; kh < 2; ++kh)
            qf[kh] = *(const f16x8*)&Qh[base + (size_t)(mrow + r) * HDIM + kh * 32 + qq * 8];

        const int Lblk = (padb == 0) ? SEQ : min(s0 + 64, kvlim);
        const int nt   = (Lblk + 63) >> 6;

        float mrun[4], lrun[4];
        f32x4 accO[4];
        #pragma unroll
        for (int i = 0; i < 4; ++i) {
            mrun[i] = -3.0e38f; lrun[i] = 0.f;
            accO[i] = (f32x4){0.f, 0.f, 0.f, 0.f};
        }

        for (int kt = 0; kt < nt; ++kt) {
            const int t0 = kt << 6;
            __syncthreads();                      // prev-tile/phase readers done
            // ---- stage K tile via gload_lds, swizzled source ----
            #pragma unroll
            for (int j = 0; j < 2; ++j) {
                const int row = j * 32 + w * 8 + srow;
                const int col = ((sslot ^ (row & 7)) << 3);
                __builtin_amdgcn_global_load_lds(
                    (const __attribute__((address_space(1))) void*)
                        &Kh[base + (size_t)(t0 + row) * HDIM + col],
                    (__attribute__((address_space(3))) void*)&Klds[(j * 32 + w * 8) * 64],
                    16, 0, 0);
            }
            // ---- stage V^T tile via gload_lds, swizzled source ----
            #pragma unroll
            for (int j = 0; j < 2; ++j) {
                const int row = j * 32 + w * 8 + srow;       // d-row
                const int col = ((sslot ^ (row & 7)) << 3);  // t-offset
                __builtin_amdgcn_global_load_lds(
                    (const __attribute__((address_space(1))) void*)
                        &VT[base + (size_t)row * SEQ + t0 + col],
                    (__attribute__((address_space(3))) void*)&Vlds[(j * 32 + w * 8) * 64],
                    16, 0, 0);
            }
            __syncthreads();

            // ---- QK^T ----
            f32x4 sacc[4];
            #pragma unroll
            for (int tg = 0; tg < 4; ++tg) sacc[tg] = (f32x4){0.f, 0.f, 0.f, 0.f};
            #pragma unroll
            for (int tg = 0; tg < 4; ++tg)
                #pragma unroll
                for (int kh = 0; kh < 2; ++kh) {
                    const int kr = tg * 16 + r;
                    const f16x8 kf = *(const f16x8*)
                        &Klds[kr * 64 + (((kh * 4 + qq) ^ (kr & 7)) << 3)];
                    sacc[tg] = __builtin_amdgcn_mfma_f32_16x16x32_f16(qf[kh], kf, sacc[tg], 0, 0, 0);
                }

            // ---- mask + online softmax (op order unchanged) ----
            float sc[4][4];
            #pragma unroll
            for (int tg = 0; tg < 4; ++tg) {
                const int tt = t0 + tg * 16 + r;
                #pragma unroll
                for (int i = 0; i < 4; ++i) {
                    const int mm = mrow + qq * 4 + i;
                    float x = sacc[tg][i] * 0.03125f;        // 1/sqrt(1024)
                    if (tt > mm || tt >= kvlim || padb == 0)
                        x -= 1.0e9f;                         // same fp op as ref
                    sc[tg][i] = x;
                }
            }
            float p[4][4], scale[4];
            #pragma unroll
            for (int i = 0; i < 4; ++i) {
                float mx = fmaxf(fmaxf(sc[0][i], sc[1][i]), fmaxf(sc[2][i], sc[3][i]));
                #pragma unroll
                for (int off = 1; off < 16; off <<= 1)
                    mx = fmaxf(mx, __shfl_xor(mx, off));
                const float mn = fmaxf(mrun[i], mx);
                scale[i] = __expf(mrun[i] - mn);
                mrun[i] = mn;
                float ls = 0.f;
                #pragma unroll
                for (int tg = 0; tg < 4; ++tg) {
                    const float pv = __expf(sc[tg][i] - mn);
                    p[tg][i] = pv;
                    ls += pv;
                }
                #pragma unroll
                for (int off = 1; off < 16; off <<= 1)
                    ls += __shfl_xor(ls, off);
                lrun[i] = lrun[i] * scale[i] + ls;
            }

            // ---- P relayout: swizzled [m][t] per-wave LDS ----
            #pragma unroll
            for (int tg = 0; tg < 4; ++tg)
                #pragma unroll
                for (int i = 0; i < 4; ++i) {
                    const int m  = qq * 4 + i;
                    const int tt = tg * 16 + r;
                    Plds[w][m * 64 + (((tt >> 3) ^ (m & 7)) << 3) + (tt & 7)] =
                        (_Float16)p[tg][i];
                }
            asm volatile("s_waitcnt lgkmcnt(0)" ::: "memory");
            __builtin_amdgcn_wave_barrier();

            f16x8 pa[2];
            #pragma unroll
            for (int kh = 0; kh < 2; ++kh)
                pa[kh] = *(const f16x8*)
                    &Plds[w][r * 64 + (((kh * 4 + qq) ^ (r & 7)) << 3)];

            // ---- PV ----
            #pragma unroll
            for (int dg = 0; dg < 4; ++dg) {
                #pragma unroll
                for (int i = 0; i < 4; ++i) accO[dg][i] *= scale[i];
                #pragma unroll
                for (int kh = 0; kh < 2; ++kh) {
                    const int vrow = dg * 16 + r;
                    const f16x8 vf = *(const f16x8*)
                        &Vlds[vrow * 64 + (((kh * 4 + qq) ^ (vrow & 7)) << 3)];
                    accO[dg] = __builtin_amdgcn_mfma_f32_16x16x32_f16(pa[kh], vf, accO[dg], 0, 0, 0);
                }
            }
        }

        // ---- phase epilogue: X f16 [B,S,H*D] ----
        #pragma unroll
        for (int dg = 0; dg < 4; ++dg)
            #pragma unroll
            for (int i = 0; i < 4; ++i)
                X[((size_t)b * SEQ + (mrow + qq * 4 + i)) * DMODEL + hh * HDIM + dg * 16 + r] =
                    (_Float16)(accO[dg][i] / lrun[i]);
    }
}

// ================= launcher ================================================
extern "C" void kernel_launch(void* const* d_in, const int* in_sizes, int n_in,
                              void* d_out, int out_size, void* d_ws, size_t ws_size,
                              hipStream_t stream)
{
    const float* Q  = (const float*)d_in[0];
    const float* K  = (const float*)d_in[1];
    const float* V  = (const float*)d_in[2];
    const int*  pad = (const int*)d_in[3];
    const float* Wq = (const float*)d_in[4];
    const float* bq = (const float*)d_in[5];
    const float* Wk = (const float*)d_in[6];
    const float* bk = (const float*)d_in[7];
    const float* Wv = (const float*)d_in[8];
    const float* bv = (const float*)d_in[9];
    const float* Wo = (const float*)d_in[10];
    const float* bo = (const float*)d_in[11];
    float* out = (float*)d_out;

    char* ws = (char*)d_ws;
    const size_t MB = 1024 * 1024;
    _Float16* Qf16 = (_Float16*)(ws + 0 * MB);
    _Float16* Kf16 = (_Float16*)(ws + 16 * MB);
    _Float16* Vf16 = (_Float16*)(ws + 32 * MB);
    _Float16* WqT  = (_Float16*)(ws + 48 * MB);
    _Float16* WkT  = (_Float16*)(ws + 50 * MB);
    _Float16* WvT  = (_Float16*)(ws + 52 * MB);
    _Float16* WoT  = (_Float16*)(ws + 54 * MB);
    _Float16* Qh   = (_Float16*)(ws + 56 * MB);
    _Float16* Kh   = (_Float16*)(ws + 72 * MB);
    _Float16* Vh   = (_Float16*)(ws + 0 * MB);    // over dead Qf16
    _Float16* VT   = (_Float16*)(ws + 16 * MB);   // over dead Kf16
    _Float16* X    = (_Float16*)(ws + 32 * MB);   // over dead Vf16

    prep_cvt<<<dim3(1024, 3), 256, 0, stream>>>(Q, K, V, Qf16, Kf16, Vf16);
    prep_tr <<<dim3(16, 16, 4), 256, 0, stream>>>(Wq, Wk, Wv, Wo, WqT, WkT, WvT, WoT);

    gemm_qkv<<<dim3(DMODEL / 128, (BATCH * SEQ) / 128, 3), 256, 0, stream>>>(
        Qf16, Kf16, Vf16, WqT, WkT, WvT, bq, bk, bv, Qh, Kh, Vh);

    transpose_v<<<dim3(SEQ / 64, BATCH * NHEAD), 256, 0, stream>>>(Vh, VT);

    attn_mfma<<<dim3(8, BATCH * NHEAD), 256, 0, stream>>>(Qh, Kh, VT, pad, X);

    gemm_out<<<dim3(DMODEL / 128, (BATCH * SEQ) / 128), 256, 0, stream>>>(X, WoT, bo, out);
}